// Round 4
// baseline (247.036 us; speedup 1.0000x reference)
//
#include <hip/hip_runtime.h>

// DecayModel: out[b,i,h] = (fwd[i] + bwd[i]) / norm[i]
//   fwd[i] = sum_{k<=i} 0.5^{i-k} x[k]   (causal IIR, decay 0.5)
//   bwd[i] = sum_{k>=i} 0.5^{k-i} x[k]   (anticausal IIR)
//   norm[i] = 4 - 2^{-i} - 2^{-(S-1-i)}  (== 4 exactly for interior i)
//
// R2 -> R4: still latency-bound (2.78 TB/s, VALUBusy 4%, occ 23%); VGPR=80
// proves fwd[32] float4 (128 regs) was NOT held in registers (spill).
//  - T=16: fwd[16] = 64 VGPRs, fits without spilling.
//  - Grid 2048 blocks (8/CU) -> 2x resident waves -> 2x outstanding loads.
//  - __launch_bounds__(256,4) caps VGPR at 128.
//  - Nontemporal stores via clang ext_vector float4 (HIP_vector_type is
//    rejected by __builtin_nontemporal_store — R3 compile fail).

constexpr int B = 16;
constexpr int S = 2048;
constexpr int H = 1024;
constexpr int T = 16;    // s-steps per tile; fwd[T] v4f in registers
constexpr int K = 12;    // halo taps: 0.5^12*6sigma ~ 1.5e-3 << 6.4e-2
constexpr int BLOCK = 256;
constexpr int HV = H / 4;  // row length in float4 units

typedef float v4f __attribute__((ext_vector_type(4)));

__global__ __launch_bounds__(BLOCK, 4) void decay_kernel(
    const v4f* __restrict__ x, v4f* __restrict__ out) {
    const int tile = blockIdx.x;   // 0..S/T-1
    const int b = blockIdx.y;      // 0..B-1
    const int s0 = tile * T;

    const size_t rowBase = (size_t)b * S * HV + threadIdx.x;  // v4f units
    const v4f* xp = x + rowBase;   // xp[s*HV] = x[b, s, 4*tid .. 4*tid+3]
    v4f* op = out + rowBase;

    // ---- left halo warm-up ----
    v4f acc = 0.0f;
    {
        int lo = s0 - K;
        if (lo < 0) lo = 0;
        for (int s = lo; s < s0; ++s)
            acc = 0.5f * acc + xp[(size_t)s * HV];
    }
    const v4f fwdm1 = acc;  // fwd value just before the tile

    // ---- forward pass over tile (single global read of the tile) ----
    v4f fwd[T];
#pragma unroll
    for (int t = 0; t < T; ++t) {
        acc = 0.5f * acc + xp[(size_t)(s0 + t) * HV];
        fwd[t] = acc;
    }

    // ---- right halo warm-up for backward pass ----
    v4f acc2 = 0.0f;
    {
        int hi = s0 + T - 1 + K;
        if (hi > S - 1) hi = S - 1;
        for (int s = hi; s >= s0 + T; --s)
            acc2 = 0.5f * acc2 + xp[(size_t)s * HV];
    }

    // ---- backward pass: x recovered from fwd registers; no tile re-read ----
    const bool interior = (s0 >= 32) && (s0 <= S - T - 32);
#pragma unroll
    for (int t = T - 1; t >= 0; --t) {
        const v4f prev = (t > 0) ? fwd[t - 1] : fwdm1;
        // x[t] = fwd[t] - 0.5*prev
        const v4f xt = fwd[t] - 0.5f * prev;
        acc2 = 0.5f * acc2 + xt;

        float rn;
        if (interior) {
            rn = 0.25f;  // norm == 4 exactly for interior i
        } else {
            const int i = s0 + t;
            const float norm =
                4.0f - exp2f((float)(-i)) - exp2f((float)(i - (S - 1)));
            rn = 1.0f / norm;
        }
        const v4f o = (fwd[t] + acc2) * rn;
        __builtin_nontemporal_store(o, &op[(size_t)(s0 + t) * HV]);
    }
}

extern "C" void kernel_launch(void* const* d_in, const int* in_sizes, int n_in,
                              void* d_out, int out_size, void* d_ws,
                              size_t ws_size, hipStream_t stream) {
    const v4f* x = (const v4f*)d_in[0];
    v4f* out = (v4f*)d_out;
    dim3 grid(S / T, B);  // 128 x 16 = 2048 blocks
    decay_kernel<<<grid, BLOCK, 0, stream>>>(x, out);
}

// Round 5
// 239.723 us; speedup vs baseline: 1.0305x; 1.0305x over previous
//
#include <hip/hip_runtime.h>

// DecayModel: out[b,i,h] = (fwd[i] + bwd[i]) / norm[i]
//   fwd[i] = sum_{k<=i} 0.5^{i-k} x[k]   (causal IIR, decay 0.5)
//   bwd[i] = sum_{k>=i} 0.5^{k-i} x[k]   (anticausal IIR)
//   norm[i] = 4 - 2^{-i} - 2^{-(S-1-i)}  (== 4 exactly for interior i)
//
// R4 -> R5: R4 was STILL latency-bound (3.25 TB/s, VALUBusy 5%) despite 43%
// occupancy. Cause: halo loops had runtime trip counts -> rolled loops with
// a serial load->waitcnt->fma round trip per iteration (24 of 40 loads/wave
// serialized, ~5 us/wave of pure latency). Fix: compile-time K trip counts,
// boundary tiles handled by wave-uniform branches (skipping == correct,
// acc starts at 0). All 40 loads now statically unrolled/hoistable.

constexpr int B = 16;
constexpr int S = 2048;
constexpr int H = 1024;
constexpr int T = 16;    // s-steps per tile; fwd[T] v4f in regs/AGPRs
constexpr int K = 12;    // halo taps: 0.5^12*6sigma ~ 1.5e-3 << 6.4e-2
constexpr int BLOCK = 256;
constexpr int HV = H / 4;     // row length in float4 units
constexpr int NTILES = S / T; // 128

typedef float v4f __attribute__((ext_vector_type(4)));

__global__ __launch_bounds__(BLOCK, 4) void decay_kernel(
    const v4f* __restrict__ x, v4f* __restrict__ out) {
    const int tile = blockIdx.x;   // 0..NTILES-1
    const int b = blockIdx.y;      // 0..B-1
    const int s0 = tile * T;

    const size_t rowBase = (size_t)b * S * HV + threadIdx.x;  // v4f units
    const v4f* xp = x + rowBase;   // xp[s*HV] = x[b, s, 4*tid .. 4*tid+3]
    v4f* op = out + rowBase;

    // ---- left halo: compile-time K loads, wave-uniform skip at tile 0 ----
    v4f acc = 0.0f;
    if (tile > 0) {
#pragma unroll
        for (int j = 0; j < K; ++j)
            acc = 0.5f * acc + xp[(size_t)(s0 - K + j) * HV];
    }
    const v4f fwdm1 = acc;  // fwd value just before the tile

    // ---- forward pass over tile (single global read of the tile) ----
    v4f fwd[T];
#pragma unroll
    for (int t = 0; t < T; ++t) {
        acc = 0.5f * acc + xp[(size_t)(s0 + t) * HV];
        fwd[t] = acc;
    }

    // ---- right halo: compile-time K loads, uniform skip at last tile ----
    v4f acc2 = 0.0f;
    if (tile < NTILES - 1) {
#pragma unroll
        for (int j = 0; j < K; ++j)
            acc2 = 0.5f * acc2 + xp[(size_t)(s0 + T + K - 1 - j) * HV];
    }

    // ---- backward pass: x recovered from fwd registers; no tile re-read ----
    const bool interior = (s0 >= 32) && (s0 <= S - T - 32);
#pragma unroll
    for (int t = T - 1; t >= 0; --t) {
        const v4f prev = (t > 0) ? fwd[t - 1] : fwdm1;
        const v4f xt = fwd[t] - 0.5f * prev;  // x[t] recovered
        acc2 = 0.5f * acc2 + xt;

        float rn;
        if (interior) {
            rn = 0.25f;  // norm == 4 exactly for interior i
        } else {
            const int i = s0 + t;
            const float norm =
                4.0f - exp2f((float)(-i)) - exp2f((float)(i - (S - 1)));
            rn = 1.0f / norm;
        }
        const v4f o = (fwd[t] + acc2) * rn;
        __builtin_nontemporal_store(o, &op[(size_t)(s0 + t) * HV]);
    }
}

extern "C" void kernel_launch(void* const* d_in, const int* in_sizes, int n_in,
                              void* d_out, int out_size, void* d_ws,
                              size_t ws_size, hipStream_t stream) {
    const v4f* x = (const v4f*)d_in[0];
    v4f* out = (v4f*)d_out;
    dim3 grid(NTILES, B);  // 128 x 16 = 2048 blocks
    decay_kernel<<<grid, BLOCK, 0, stream>>>(x, out);
}

// Round 6
// 236.013 us; speedup vs baseline: 1.0467x; 1.0157x over previous
//
#include <hip/hip_runtime.h>

// DecayModel: out[b,i,h] = (fwd[i] + bwd[i]) / norm[i]
//   fwd[i] = sum_{k<=i} 0.5^{i-k} x[k],  bwd[i] = sum_{k>=i} 0.5^{k-i} x[k]
//   norm[i] = 4 - 2^{-i} - 2^{-(S-1-i)}  (== 4 exactly for interior i)
//
// R5 -> R6: BW stuck at 3.4 TB/s with VALUBusy 5% at 44% occupancy.
// VGPR=48 => compiler serialized the load/fma chain into tiny batches
// (~1 load in flight/wave => ~15us/wave-pass => ~3.8 TB/s device: matches).
// Fix: batch ALL R=40 row-loads into an explicit v4f xv[40] register array
// under __launch_bounds__(256,2) (256-VGPR budget). 40 loads issue with no
// intervening waits -> ~40KB in flight per wave. Occupancy drops to 8
// waves/CU -- intentionally: 8 x 40KB/CU in flight >> what 6.3 TB/s needs.
// Boundary tiles are branch-free: clamped addresses + zeroed OOB values.

constexpr int B = 16;
constexpr int S = 2048;
constexpr int H = 1024;
constexpr int T = 16;          // tile s-steps
constexpr int K = 12;          // halo taps: 0.5^12*6sigma ~ 1.5e-3 << 6.4e-2
constexpr int R = T + 2 * K;   // 40 rows held in registers
constexpr int BLOCK = 256;
constexpr int HV = H / 4;      // row length in float4 units
constexpr int NTILES = S / T;  // 128

typedef float v4f __attribute__((ext_vector_type(4)));

__global__ __launch_bounds__(BLOCK, 2) void decay_kernel(
    const v4f* __restrict__ x, v4f* __restrict__ out) {
    const int tile = blockIdx.x;   // 0..NTILES-1
    const int b = blockIdx.y;      // 0..B-1
    const int s0 = tile * T;

    const size_t rowBase = (size_t)b * S * HV + threadIdx.x;  // v4f units
    const v4f* xp = x + rowBase;   // xp[s*HV] = x[b, s, 4*tid .. 4*tid+3]
    v4f* op = out + rowBase;

    // ---- batch-load all R rows into registers (clamped addresses) ----
    v4f xv[R];
#pragma unroll
    for (int j = 0; j < R; ++j) {
        int s = s0 - K + j;
        int sc = s < 0 ? 0 : (s > S - 1 ? S - 1 : s);
        xv[j] = xp[(size_t)sc * HV];
    }
    // zero out-of-range halo rows (wave-uniform selects; only first/last
    // tiles ever trigger)
#pragma unroll
    for (int j = 0; j < R; ++j) {
        int s = s0 - K + j;
        if (s < 0 || s > S - 1) xv[j] = 0.0f;
    }

    // ---- forward recurrence; overwrite xv[j] with fwd[j] for the rows
    //      whose fwd value is needed (j = K-1 .. K+T-1) ----
    {
        v4f acc = 0.0f;
#pragma unroll
        for (int j = 0; j < K + T; ++j) {
            acc = 0.5f * acc + xv[j];
            if (j >= K - 1) xv[j] = acc;  // fwd stored in place
        }
    }

    // ---- backward recurrence + combine ----
    const bool interior = (s0 >= 32) && (s0 <= S - T - 32);
    {
        v4f acc2 = 0.0f;
#pragma unroll
        for (int j = R - 1; j >= K; --j) {
            v4f xt;
            if (j >= K + T) {
                xt = xv[j];                          // raw x (right halo)
            } else {
                xt = xv[j] - 0.5f * xv[j - 1];       // recover x from fwd
            }
            acc2 = 0.5f * acc2 + xt;
            if (j < K + T) {
                const int i = s0 + (j - K);
                float rn;
                if (interior) {
                    rn = 0.25f;  // norm == 4 exactly for interior i
                } else {
                    const float norm = 4.0f - exp2f((float)(-i)) -
                                       exp2f((float)(i - (S - 1)));
                    rn = 1.0f / norm;
                }
                const v4f o = (xv[j] + acc2) * rn;
                __builtin_nontemporal_store(o, &op[(size_t)i * HV]);
            }
        }
    }
}

extern "C" void kernel_launch(void* const* d_in, const int* in_sizes, int n_in,
                              void* d_out, int out_size, void* d_ws,
                              size_t ws_size, hipStream_t stream) {
    const v4f* x = (const v4f*)d_in[0];
    v4f* out = (v4f*)d_out;
    dim3 grid(NTILES, B);  // 128 x 16 = 2048 blocks
    decay_kernel<<<grid, BLOCK, 0, stream>>>(x, out);
}